// Round 1
// 620.975 us; speedup vs baseline: 1.0314x; 1.0314x over previous
//
#include <hip/hip_runtime.h>
#include <hip/hip_bf16.h>

// Problem dims (fixed by reference setup_inputs)
#define B_DIM 2048
#define D_DIM 512
#define C_DIM 32000
#define SCALE_F 32.0f
#define MARGIN_F 16.0f   // M * SCALE = 0.5 * 32

typedef unsigned short ushort_t;
typedef __bf16 bf16x8 __attribute__((ext_vector_type(8)));
typedef float floatx4 __attribute__((ext_vector_type(4)));
typedef unsigned short ushort4v __attribute__((ext_vector_type(4)));

// round-to-nearest-even fp32 -> bf16 (inputs are finite normals; no NaN path needed)
__device__ __forceinline__ unsigned short f2bf(float f) {
  union { float f; unsigned int u; } v; v.f = f;
  unsigned int u = v.u;
  u += 0x7FFFu + ((u >> 16) & 1u);
  return (unsigned short)(u >> 16);
}

// ---------------------------------------------------------------------------
// Pass 1: L2-normalize rows of x [2048,512] and weight [32000,512] (fp32),
// emit bf16 rows into workspace. One wave per row (512 elems = 8/lane).
// ---------------------------------------------------------------------------
__global__ __launch_bounds__(256) void normalize_kernel(
    const float* __restrict__ x, const float* __restrict__ w,
    ushort_t* __restrict__ xn, ushort_t* __restrict__ wn) {
  int gwave = (int)((blockIdx.x * 256 + threadIdx.x) >> 6);
  int lane = threadIdx.x & 63;
  const float* src;
  ushort_t* dst;
  if (gwave < B_DIM) {
    src = x + (size_t)gwave * D_DIM;
    dst = xn + (size_t)gwave * D_DIM;
  } else {
    int r = gwave - B_DIM;
    src = w + (size_t)r * D_DIM;
    dst = wn + (size_t)r * D_DIM;
  }
  const float4* s4 = (const float4*)src;
  float4 v0 = s4[lane];        // cols 4*lane   .. 4*lane+3
  float4 v1 = s4[64 + lane];   // cols 256+4*lane ..
  float s = v0.x * v0.x + v0.y * v0.y + v0.z * v0.z + v0.w * v0.w
          + v1.x * v1.x + v1.y * v1.y + v1.z * v1.z + v1.w * v1.w;
#pragma unroll
  for (int off = 32; off > 0; off >>= 1) s += __shfl_xor(s, off, 64);
  float inv = 1.0f / fmaxf(sqrtf(s), 1e-12f);
  ushort4v o0, o1;
  o0.x = f2bf(v0.x * inv); o0.y = f2bf(v0.y * inv);
  o0.z = f2bf(v0.z * inv); o0.w = f2bf(v0.w * inv);
  o1.x = f2bf(v1.x * inv); o1.y = f2bf(v1.y * inv);
  o1.z = f2bf(v1.z * inv); o1.w = f2bf(v1.w * inv);
  ((ushort4v*)dst)[lane] = o0;
  ((ushort4v*)dst)[64 + lane] = o1;
}

// ---------------------------------------------------------------------------
// Pass 2: C[2048,32000] = (Xn @ Wn^T) * 32, written to BOTH output halves;
// loss half gets -16 at (row, targets[row]) fused in the epilogue.
// 128x128 tile, BK=64 (half the barrier drains of BK=32 at K=512), 4 waves,
// 16x16x32 bf16 MFMA, global_load_lds width=16 staging.
// LDS is XOR-swizzled (chunk ^= row&7) via PRE-SWIZZLED GLOBAL SOURCE
// (gload_lds writes linearly; rule: linear dest + inv-swz source + swz read)
// -> ds_read_b128 bank conflicts drop from 8/16-way to free 2-way.
// Output stores are NONTEMPORAL: 524 MB streams must not evict A/B tiles
// from L2 (that eviction is the theory for the 3-6x gap vs the 912 TF bench).
// ---------------------------------------------------------------------------
__device__ __forceinline__ void gload_lds16(const ushort_t* g, ushort_t* l) {
  __builtin_amdgcn_global_load_lds(
      (const __attribute__((address_space(1))) void*)g,
      (__attribute__((address_space(3))) void*)l, 16, 0, 0);
}

__global__ __launch_bounds__(256) void gemm_margin_kernel(
    const ushort_t* __restrict__ A,    // [2048][512]  normalized bf16
    const ushort_t* __restrict__ Bw,   // [32000][512] normalized bf16
    const int* __restrict__ targets,   // [2048]
    float* __restrict__ out_loss, float* __restrict__ out_pred) {
  __shared__ __align__(16) ushort_t As[128 * 64];   // 16 KB, [row][chunk^ (row&7)]
  __shared__ __align__(16) ushort_t Bs[128 * 64];   // 16 KB
  __shared__ int tg[128];

  int tid = threadIdx.x;
  int wave = tid >> 6;
  int lane = tid & 63;

  // Bijective XCD-aware swizzle: 4000 blocks, 4000 % 8 == 0.
  // HW round-robins blockIdx across 8 XCDs; remap so each XCD owns a
  // contiguous work range -> the 16 blocks sharing a B-tile (same bn)
  // run on the same XCD's L2, A (2 MB) stays resident per-XCD.
  int bid = (int)blockIdx.x;
  int work = (bid & 7) * 500 + (bid >> 3);
  int bm = work & 15;   // 16 M-blocks (consecutive works share a B-tile)
  int bn = work >> 4;   // 250 N-blocks

  if (tid < 128) tg[tid] = targets[bm * 128 + tid];

  int wm = wave & 1;   // 2x2 wave grid over the 128x128 tile
  int wn = wave >> 1;

  // staging: per issue, 256 thr x 16B = 32 rows x 128B; thread -> (row, chunk)
  // source pre-swizzle: this lane loads global chunk (c ^ (row&7)) so that
  // linear LDS slot (row, c) holds G(row, c ^ (row&7)).
  int srow = tid >> 3;                      // 0..31 within an issue
  int schunk = (tid & 7) ^ (srow & 7);      // pre-swizzled 16B chunk index
  const ushort_t* gA = A + (size_t)(bm * 128 + srow) * D_DIM + schunk * 8;
  const ushort_t* gB = Bw + (size_t)(bn * 128 + srow) * D_DIM + schunk * 8;

  // LDS dest is wave-uniform base + lane*16 (HW rule); issue q covers rows q*32..+31
  ushort_t* lA = As + wave * 512;   // + q*2048 per issue
  ushort_t* lB = Bs + wave * 512;

  floatx4 acc[4][4];
#pragma unroll
  for (int i = 0; i < 4; i++)
#pragma unroll
    for (int j = 0; j < 4; j++) acc[i][j] = {0.0f, 0.0f, 0.0f, 0.0f};

  int fm = lane & 15;   // M (or N) index within 16-tile
  int q4 = lane >> 4;   // K quad (8 elems each)

  for (int k0 = 0; k0 < D_DIM; k0 += 64) {
    __syncthreads();  // previous iter's LDS reads done before overwrite
#pragma unroll
    for (int q = 0; q < 4; q++) {
      gload_lds16(gA + (size_t)q * 32 * D_DIM, lA + q * 2048);
      gload_lds16(gB + (size_t)q * 32 * D_DIM, lB + q * 2048);
    }
    gA += 64;
    gB += 64;
    __syncthreads();  // compiler drains vmcnt(0) before s_barrier

#pragma unroll
    for (int kk = 0; kk < 2; kk++) {
      bf16x8 af[4], bfr[4];
#pragma unroll
      for (int i = 0; i < 4; i++) {
        int row = wm * 64 + i * 16 + fm;
        int chunk = (kk * 4 + q4) ^ (fm & 7);   // row&7 == fm&7 here
        af[i] = *(const bf16x8*)(As + row * 64 + chunk * 8);
      }
#pragma unroll
      for (int j = 0; j < 4; j++) {
        int row = wn * 64 + j * 16 + fm;
        int chunk = (kk * 4 + q4) ^ (fm & 7);
        bfr[j] = *(const bf16x8*)(Bs + row * 64 + chunk * 8);
      }
#pragma unroll
      for (int i = 0; i < 4; i++)
#pragma unroll
        for (int j = 0; j < 4; j++)
          acc[i][j] = __builtin_amdgcn_mfma_f32_16x16x32_bf16(af[i], bfr[j], acc[i][j], 0, 0, 0);
    }
  }

  // Epilogue. C/D layout (16x16x32): col = lane&15, row = (lane>>4)*4 + reg.
  // Nontemporal: 524 MB of pure streaming writes must not thrash L2.
  int col = lane & 15;
  int gn0 = bn * 128 + wn * 64;
#pragma unroll
  for (int i = 0; i < 4; i++) {
#pragma unroll
    for (int r = 0; r < 4; r++) {
      int lm = wm * 64 + i * 16 + (lane >> 4) * 4 + r;  // row within block tile
      int gm = bm * 128 + lm;
      int t = tg[lm];
      size_t rowoff = (size_t)gm * C_DIM;
#pragma unroll
      for (int j = 0; j < 4; j++) {
        int gn = gn0 + j * 16 + col;
        float v = acc[i][j][r] * SCALE_F;
        __builtin_nontemporal_store(v, &out_pred[rowoff + gn]);
        __builtin_nontemporal_store((gn == t) ? (v - MARGIN_F) : v,
                                    &out_loss[rowoff + gn]);
      }
    }
  }
}

extern "C" void kernel_launch(void* const* d_in, const int* in_sizes, int n_in,
                              void* d_out, int out_size, void* d_ws, size_t ws_size,
                              hipStream_t stream) {
  const float* x = (const float*)d_in[0];
  const float* w = (const float*)d_in[1];
  const int* targets = (const int*)d_in[2];

  float* out_loss = (float*)d_out;                       // first tuple element
  float* out_pred = out_loss + (size_t)B_DIM * C_DIM;    // second tuple element

  ushort_t* xn = (ushort_t*)d_ws;                        // 2048*512 bf16 = 2 MB
  ushort_t* wn = xn + (size_t)B_DIM * D_DIM;             // 32000*512 bf16 = 32.75 MB

  // 2048 + 32000 = 34048 rows, one wave each, 4 waves/block
  normalize_kernel<<<(B_DIM + C_DIM) / 4, 256, 0, stream>>>(x, w, xn, wn);

  // 16 x 250 = 4000 blocks
  gemm_margin_kernel<<<(B_DIM / 128) * (C_DIM / 128), 256, 0, stream>>>(
      xn, wn, targets, out_loss, out_pred);
}